// Round 14
// baseline (9324.746 us; speedup 1.0000x reference)
//
#include <hip/hip_runtime.h>
#include <math.h>

#define NTHR 512
typedef unsigned long long u64;

// ---------------------------------------------------------------- helpers
__device__ __forceinline__ void st_uc(float* p, float v) {
    asm volatile("global_store_dword %0, %1, off sc0 sc1" :: "v"(p), "v"(v) : "memory");
}
#define LGKM0_BAR do { \
    asm volatile("s_waitcnt lgkmcnt(0)" ::: "memory"); \
    __builtin_amdgcn_s_barrier(); \
} while (0)

// ---------------------------------------------------------------- init
// hp/gp: 2 slots x 32 batches x 1024 of (step:u32 | value:f32) pairs.
// hp counter 0xFFFFFFFF = (unsigned)(-1) = expected at k=0 (value 0 = h(-1)).
__global__ void init_kernel(u64* hp, u64* gp) {
    int i = blockIdx.x * blockDim.x + threadIdx.x;
    if (i < 65536) {
        __hip_atomic_store(hp + i, 0xFFFFFFFF00000000ull, __ATOMIC_RELAXED, __HIP_MEMORY_SCOPE_AGENT);
        __hip_atomic_store(gp + i, 0xFFFFFFFE00000000ull, __ATOMIC_RELAXED, __HIP_MEMORY_SCOPE_AGENT);
    }
}

// ---------------------------------------------------------------- xb = x @ b
__global__ __launch_bounds__(256) void xb_gemm(const float* __restrict__ X,
                                               const float* __restrict__ Bw,
                                               float* __restrict__ XB) {
    __shared__ float xs[16][132];
    __shared__ float bs[16][132];
    const int bm = blockIdx.x >> 3;
    const int bn = blockIdx.x & 7;
    const int m0 = bm * 128, n0 = bn * 128;
    const int tid = threadIdx.x;
    const int tx = tid & 15, ty = tid >> 4;
    float acc[8][8];
#pragma unroll
    for (int i = 0; i < 8; ++i)
#pragma unroll
        for (int j = 0; j < 8; ++j) acc[i][j] = 0.f;

    for (int k0 = 0; k0 < 1024; k0 += 16) {
#pragma unroll
        for (int p = 0; p < 2; ++p) {
            int f = tid + p * 256;
            int m = f >> 2, kq = f & 3;
            float4 v = *(const float4*)&X[(size_t)(m0 + m) * 1024 + k0 + kq * 4];
            xs[kq * 4 + 0][m] = v.x; xs[kq * 4 + 1][m] = v.y;
            xs[kq * 4 + 2][m] = v.z; xs[kq * 4 + 3][m] = v.w;
        }
#pragma unroll
        for (int p = 0; p < 2; ++p) {
            int f = tid + p * 256;
            int k = f >> 5, n = (f & 31) * 4;
            float4 v = *(const float4*)&Bw[(size_t)(k0 + k) * 1024 + n0 + n];
            *(float4*)&bs[k][n] = v;
        }
        __syncthreads();
#pragma unroll
        for (int k = 0; k < 16; ++k) {
            float xv[8], bv[8];
            *(float4*)&xv[0] = *(const float4*)&xs[k][ty * 8];
            *(float4*)&xv[4] = *(const float4*)&xs[k][ty * 8 + 4];
            *(float4*)&bv[0] = *(const float4*)&bs[k][tx * 8];
            *(float4*)&bv[4] = *(const float4*)&bs[k][tx * 8 + 4];
#pragma unroll
            for (int i = 0; i < 8; ++i)
#pragma unroll
                for (int j = 0; j < 8; ++j) acc[i][j] += xv[i] * bv[j];
        }
        __syncthreads();
    }
#pragma unroll
    for (int i = 0; i < 8; ++i)
#pragma unroll
        for (int j = 0; j < 8; j += 4) {
            float4 v = make_float4(acc[i][j], acc[i][j + 1], acc[i][j + 2], acc[i][j + 3]);
            *(float4*)&XB[(size_t)(m0 + ty * 8 + i) * 1024 + n0 + tx * 8 + j] = v;
        }
}

// ---------------------------------------------------------------- persistent scan
// 256 WGs = 4 bg (8 batches) x 64 slices (16 cols). ONE stream per WG, 2
// sub-phases per step (overhead paid 2x, not 4x). Compute core = r3-verified
// 8x8 blocking + 6-level distributing butterfly. Exchange = r10 in-band
// (value,step) pairs, raw lgkm-only barriers (r11). scr aliases staging head;
// scr value (kq,cg,slot) stored at float 64*(slot>>3)+32*cg+4*(slot&7)+kq so
// epi thread X reads exactly f4 X (own b128) and only thread X rewrites f4 X
// in the next stage -> no epi/stage race, 3 barriers per sub-phase.
__global__ __launch_bounds__(NTHR, 1) void scan_kernel(
    const float* __restrict__ A, const float* __restrict__ CTm,
    float* __restrict__ XBH, u64* __restrict__ hp, u64* __restrict__ gp,
    float* __restrict__ ht_out, float* __restrict__ ct_out) {
    extern __shared__ float lds[];
    float* a_lf  = lds;                    // 16384 floats (64KB) col-major
    float* ct_lf = lds + 16384;            // 16384 floats (64KB)
    float* stgf  = lds + 32768;            // 8192 floats (32KB); scr = head 512
    float* scrf  = stgf;
    const float4* a_l4  = (const float4*)a_lf;
    const float4* ct_l4 = (const float4*)ct_lf;
    float4* stg4 = (float4*)stgf;

    const int wg  = blockIdx.x;
    const int bg  = wg >> 6;               // 0..3 (8 batches each)
    const int sg  = wg & 63;
    const int c0wg = sg * 16;
    const int tid = threadIdx.x;

    // ---- one-time weight preload: cols c0wg..c0wg+15, col-major ----
    {
        const int c = tid & 15, i0 = tid >> 4;
        for (int i = i0; i < 1024; i += 32) {
            a_lf[c * 1024 + i]  = A[(size_t)i * 1024 + c0wg + c];
            ct_lf[c * 1024 + i] = CTm[(size_t)i * 1024 + c0wg + c];
        }
    }

    const int L  = tid & 63;
    const int w  = tid >> 6;
    const int Lc = L & 7;
    const int Lb = (L >> 3) & 7;
    const int cg = w & 1, kq = w >> 1;     // col half; k-quarter (== gate in B)

    int wIdx[8], sIdx[8];
#pragma unroll
    for (int c = 0; c < 8; ++c) wIdx[c] = (cg * 8 + (c ^ Lc)) * 256 + kq * 64 + L;
#pragma unroll
    for (int r = 0; r < 8; ++r) sIdx[r] = ((r ^ Lb) << 8) + kq * 64 + L;

    // scr write position (see header comment)
    const int scrpos = 64 * (L >> 3) + 32 * cg + 4 * (L & 7) + kq;

    // epi mapping (tid < 128): 1 output/thread
    const int e_b   = tid >> 4;            // 0..7
    const int e_j   = tid & 15;
    const int col   = c0wg + e_j;
    const int bglob = bg * 8 + e_b;

    float creg = 0.f;                      // cell state (epi threads)
    u64 qpf[16];

    auto issue_pf = [&](const u64* base) {
#pragma unroll
        for (int j = 0; j < 16; ++j)
            qpf[j] = __hip_atomic_load(base + (j >> 2) * 2048 + 4 * tid + (j & 3),
                                       __ATOMIC_RELAXED, __HIP_MEMORY_SCOPE_AGENT);
    };
    // validate prefetched pairs (retry reloads), then unpack into staging
    auto validate_stage = [&](const u64* base, unsigned expect) {
        for (;;) {
            bool ok = true;
#pragma unroll
            for (int j = 0; j < 16; ++j) ok &= ((unsigned)(qpf[j] >> 32) == expect);
            if (!__any(!ok)) break;
            __builtin_amdgcn_s_sleep(1);
#pragma unroll
            for (int j = 0; j < 16; ++j)
                qpf[j] = __hip_atomic_load(base + (j >> 2) * 2048 + 4 * tid + (j & 3),
                                           __ATOMIC_RELAXED, __HIP_MEMORY_SCOPE_AGENT);
        }
#pragma unroll
        for (int c = 0; c < 4; ++c) {
            float4 f = make_float4(__uint_as_float((unsigned)qpf[4 * c]),
                                   __uint_as_float((unsigned)qpf[4 * c + 1]),
                                   __uint_as_float((unsigned)qpf[4 * c + 2]),
                                   __uint_as_float((unsigned)qpf[4 * c + 3]));
            stg4[c * 512 + tid] = f;
        }
    };
    // r3-verified compute core: 64 dot4s + 6-level distributing butterfly
    auto compute = [&](const float4* wmat) -> float {
        float4 sv[8], wv[8];
#pragma unroll
        for (int r = 0; r < 8; ++r) sv[r] = stg4[sIdx[r]];
#pragma unroll
        for (int c = 0; c < 8; ++c) wv[c] = wmat[wIdx[c]];
        float v[64];
#pragma unroll
        for (int r = 0; r < 8; ++r)
#pragma unroll
            for (int c = 0; c < 8; ++c)
                v[r * 8 + c] = sv[r].x * wv[c].x + sv[r].y * wv[c].y
                             + sv[r].z * wv[c].z + sv[r].w * wv[c].w;
#pragma unroll
        for (int j = 0; j < 32; ++j) v[j] = v[2 * j] + __shfl_xor(v[2 * j + 1], 1);
#pragma unroll
        for (int j = 0; j < 16; ++j) v[j] = v[2 * j] + __shfl_xor(v[2 * j + 1], 2);
#pragma unroll
        for (int j = 0; j < 8; ++j)  v[j] = v[2 * j] + __shfl_xor(v[2 * j + 1], 4);
#pragma unroll
        for (int j = 0; j < 4; ++j)  v[j] = v[2 * j] + __shfl_xor(v[2 * j + 1], 8);
#pragma unroll
        for (int j = 0; j < 2; ++j)  v[j] = v[2 * j] + __shfl_xor(v[2 * j + 1], 16);
        return v[0] + __shfl_xor(v[1], 32);
    };

    __syncthreads();                       // weights ready
    issue_pf(hp + 32768 + (size_t)bg * 8192);   // prologue: h(-1), slot 1

    for (int k = 0; k < 512; ++k) {
        const size_t hsl = (size_t)((k + 1) & 1) * 32768;   // h(k-1) slot
        const size_t gsl = (size_t)(k & 1) * 32768;         // g(k)/h(k) slot

        // xb for this step's epi-A (plain cached load, in flight until use)
        float xbv = 0.f;
        if (tid < 128) xbv = XBH[((size_t)bglob * 512 + k) * 1024 + col];

        // ================= phase A: g(k) = (h(k-1) @ A) * xb =================
        validate_stage(hp + hsl + (size_t)bg * 8192, (unsigned)(k - 1));
        LGKM0_BAR;                          // B1: staged
        float r = compute(a_l4);
        issue_pf(gp + gsl + (size_t)bg * 8192);   // g(k) sample (in flight)
        LGKM0_BAR;                          // B2: staging reads done
        scrf[scrpos] = r;
        LGKM0_BAR;                          // B3: scr visible
        if (tid < 128) {                    // epi-A: own f4 only
            float4 sq = ((const float4*)scrf)[tid];
            float gval = (sq.x + sq.y + sq.z + sq.w) * xbv;
            u64 pk = ((u64)(unsigned)k << 32) | (u64)__float_as_uint(gval);
            __hip_atomic_store(gp + gsl + (size_t)bglob * 1024 + col, pk,
                               __ATOMIC_RELAXED, __HIP_MEMORY_SCOPE_AGENT);
        }

        // ================= phase B: gates + cell update =================
        validate_stage(gp + gsl + (size_t)bg * 8192, (unsigned)k);
        LGKM0_BAR;                          // B1'
        r = compute(ct_l4);
        issue_pf(hp + gsl + (size_t)bg * 8192);   // h(k) sample for A(k+1)
        LGKM0_BAR;                          // B2'
        scrf[scrpos] = r;
        LGKM0_BAR;                          // B3'
        if (tid < 128) {                    // epi-B: gates in own f4 (f,i,g,o)
            float4 sq = ((const float4*)scrf)[tid];
            float ft = 1.f / (1.f + __expf(-sq.x));
            float it = 1.f / (1.f + __expf(-sq.y));
            float gt = tanhf(sq.z);
            float ot = 1.f / (1.f + __expf(-sq.w));
            creg = ft * creg + it * gt;
            float hv = ot * tanhf(creg);
            u64 pk = ((u64)(unsigned)k << 32) | (u64)__float_as_uint(hv);
            __hip_atomic_store(hp + gsl + (size_t)bglob * 1024 + col, pk,
                               __ATOMIC_RELAXED, __HIP_MEMORY_SCOPE_AGENT);
            st_uc(XBH + ((size_t)bglob * 512 + k) * 1024 + col, hv);
            if (k == 511) {
                st_uc(ht_out + (size_t)bglob * 1024 + col, hv);
                st_uc(ct_out + (size_t)bglob * 1024 + col, creg);
            }
        }
    }
}

// ---------------------------------------------------------------- launch
extern "C" void kernel_launch(void* const* d_in, const int* in_sizes, int n_in,
                              void* d_out, int out_size, void* d_ws, size_t ws_size,
                              hipStream_t stream) {
    const float* X   = (const float*)d_in[0];
    const float* A   = (const float*)d_in[1];
    const float* Bw  = (const float*)d_in[2];
    const float* CTm = (const float*)d_in[3];

    float* out    = (float*)d_out;
    float* XBH    = out;                                  // xb in, hidden_seq out
    float* ht_out = out + (size_t)32 * 512 * 1024;
    float* ct_out = ht_out + 32 * 1024;

    u64* hp = (u64*)d_ws;                                 // 65536 pairs (512KB)
    u64* gp = hp + 65536;                                 // 65536 pairs (512KB)

    (void)hipFuncSetAttribute((const void*)scan_kernel,
                              hipFuncAttributeMaxDynamicSharedMemorySize, 163840);

    init_kernel<<<dim3(256), dim3(256), 0, stream>>>(hp, gp);
    xb_gemm<<<dim3(1024), dim3(256), 0, stream>>>(X, Bw, XBH);
    scan_kernel<<<dim3(256), dim3(NTHR), 163840, stream>>>(A, CTm, XBH, hp, gp,
                                                           ht_out, ct_out);
}

// Round 15
// 6173.434 us; speedup vs baseline: 1.5105x; 1.5105x over previous
//
#include <hip/hip_runtime.h>
#include <math.h>

typedef unsigned long long u64;

// ---------------------------------------------------------------- helpers
__device__ __forceinline__ void st_uc(float* p, float v) {
    asm volatile("global_store_dword %0, %1, off sc0 sc1" :: "v"(p), "v"(v) : "memory");
}
#define LGKM0_BAR do { \
    asm volatile("s_waitcnt lgkmcnt(0)" ::: "memory"); \
    __builtin_amdgcn_s_barrier(); \
} while (0)

// ---------------------------------------------------------------- init
// hp/gp: 2 slots x 32 batches x 1024 of (step:u32 | value:f32) pairs.
__global__ void init_kernel(u64* hp, u64* gp) {
    int i = blockIdx.x * blockDim.x + threadIdx.x;
    if (i < 65536) {
        __hip_atomic_store(hp + i, 0xFFFFFFFF00000000ull, __ATOMIC_RELAXED, __HIP_MEMORY_SCOPE_AGENT);
        __hip_atomic_store(gp + i, 0xFFFFFFFE00000000ull, __ATOMIC_RELAXED, __HIP_MEMORY_SCOPE_AGENT);
    }
}

// ---------------------------------------------------------------- xb = x @ b
__global__ __launch_bounds__(256) void xb_gemm(const float* __restrict__ X,
                                               const float* __restrict__ Bw,
                                               float* __restrict__ XB) {
    __shared__ float xs[16][132];
    __shared__ float bs[16][132];
    const int bm = blockIdx.x >> 3;
    const int bn = blockIdx.x & 7;
    const int m0 = bm * 128, n0 = bn * 128;
    const int tid = threadIdx.x;
    const int tx = tid & 15, ty = tid >> 4;
    float acc[8][8];
#pragma unroll
    for (int i = 0; i < 8; ++i)
#pragma unroll
        for (int j = 0; j < 8; ++j) acc[i][j] = 0.f;

    for (int k0 = 0; k0 < 1024; k0 += 16) {
#pragma unroll
        for (int p = 0; p < 2; ++p) {
            int f = tid + p * 256;
            int m = f >> 2, kq = f & 3;
            float4 v = *(const float4*)&X[(size_t)(m0 + m) * 1024 + k0 + kq * 4];
            xs[kq * 4 + 0][m] = v.x; xs[kq * 4 + 1][m] = v.y;
            xs[kq * 4 + 2][m] = v.z; xs[kq * 4 + 3][m] = v.w;
        }
#pragma unroll
        for (int p = 0; p < 2; ++p) {
            int f = tid + p * 256;
            int k = f >> 5, n = (f & 31) * 4;
            float4 v = *(const float4*)&Bw[(size_t)(k0 + k) * 1024 + n0 + n];
            *(float4*)&bs[k][n] = v;
        }
        __syncthreads();
#pragma unroll
        for (int k = 0; k < 16; ++k) {
            float xv[8], bv[8];
            *(float4*)&xv[0] = *(const float4*)&xs[k][ty * 8];
            *(float4*)&xv[4] = *(const float4*)&xs[k][ty * 8 + 4];
            *(float4*)&bv[0] = *(const float4*)&bs[k][tx * 8];
            *(float4*)&bv[4] = *(const float4*)&bs[k][tx * 8 + 4];
#pragma unroll
            for (int i = 0; i < 8; ++i)
#pragma unroll
                for (int j = 0; j < 8; ++j) acc[i][j] += xv[i] * bv[j];
        }
        __syncthreads();
    }
#pragma unroll
    for (int i = 0; i < 8; ++i)
#pragma unroll
        for (int j = 0; j < 8; j += 4) {
            float4 v = make_float4(acc[i][j], acc[i][j + 1], acc[i][j + 2], acc[i][j + 3]);
            *(float4*)&XB[(size_t)(m0 + ty * 8 + i) * 1024 + n0 + tx * 8 + j] = v;
        }
}

// ---------------------------------------------------------------- persistent scan
// 512 WGs x 256 threads (2 WGs/CU): bgpair p in 0..3 (streams bg=p, p+4 of 4
// batches), slice in 0..127 (8 cols). LDS = 32KB A + 32KB CT + 16KB staging =
// 81920B exactly -> two co-resident WGs give hardware stall overlap (TLP).
// Each wave owns 2 cols end-to-end: in-lane q-sum + short distributing
// butterfly -> inline epilogue+publish, no scr, no deferred epi.
// Exchange = r10/r11 in-band (value,step) pairs, raw lgkm-only barriers,
// prefetch at sub-phase end (every edge keeps >=1 sub-phase slack).
__global__ __launch_bounds__(256, 2) void scan_kernel(
    const float* __restrict__ A, const float* __restrict__ CTm,
    float* __restrict__ XBH, u64* __restrict__ hp, u64* __restrict__ gp,
    float* __restrict__ ht_out, float* __restrict__ ct_out) {
    extern __shared__ float lds[];
    float* a_lf  = lds;                    // [8 cols][1024] col-major (32KB)
    float* ct_lf = lds + 8192;             // (32KB)
    float* stgf  = lds + 16384;            // 4096 floats (16KB) shared staging
    const float4* a_l4  = (const float4*)a_lf;
    const float4* ct_l4 = (const float4*)ct_lf;
    const float4* st4   = (const float4*)stgf;

    const int wg  = blockIdx.x;
    const int bp  = wg >> 7;               // 0..3
    const int bg0 = bp, bg1 = bp + 4;
    const int sl  = wg & 127;
    const int c0wg = sl * 8;
    const int tid = threadIdx.x;

    // ---- one-time weight preload: cols c0wg..c0wg+7, col-major ----
    {
        const int c = tid & 7, i0 = tid >> 3;   // 32 threads per col
        for (int i = i0; i < 1024; i += 32) {
            a_lf[c * 1024 + i]  = A[(size_t)i * 1024 + c0wg + c];
            ct_lf[c * 1024 + i] = CTm[(size_t)i * 1024 + c0wg + c];
        }
    }

    const int L  = tid & 63;
    const int w  = tid >> 6;               // 0..3, owns cols wc, wc+1
    const int wc = 2 * w;
    // phase-A lane keys: slot s=r*2+c; c<->bit0, r<->bits1-2
    const int Lc = L & 1, Lb = (L >> 1) & 3;
    // phase-B lane keys: slot s=b*8+j*4+gt; gt<->bits0-1, j<->bit2, b<->bits3-4
    const int Lg = L & 3, Lj = (L >> 2) & 1, Lbb = (L >> 3) & 3;

    // A-epi lanes (L<8): b=(L>>1)&3, c=L&1
    const int a_b = (L >> 1) & 3, a_col = c0wg + wc + (L & 1);
    // B-epi lanes (L<32 && (L&3)==0): b=(L>>3)&3, j=(L>>2)&1
    const int b_b = (L >> 3) & 3, b_col = c0wg + wc + ((L >> 2) & 1);

    float creg0 = 0.f, creg1 = 0.f;        // B-epi lanes: cell state per stream
    u64 qpf[16];

    auto issue_pf = [&](const u64* base) {
#pragma unroll
        for (int j = 0; j < 16; ++j)
            qpf[j] = __hip_atomic_load(base + tid + 256 * j, __ATOMIC_RELAXED,
                                       __HIP_MEMORY_SCOPE_AGENT);
    };
    auto validate_stage = [&](const u64* base, unsigned expect) {
        for (;;) {
            bool ok = true;
#pragma unroll
            for (int j = 0; j < 16; ++j) ok &= ((unsigned)(qpf[j] >> 32) == expect);
            if (!__any(!ok)) break;
            __builtin_amdgcn_s_sleep(1);
#pragma unroll
            for (int j = 0; j < 16; ++j)
                qpf[j] = __hip_atomic_load(base + tid + 256 * j, __ATOMIC_RELAXED,
                                           __HIP_MEMORY_SCOPE_AGENT);
        }
#pragma unroll
        for (int j = 0; j < 16; ++j) stgf[tid + 256 * j] = __uint_as_float((unsigned)qpf[j]);
    };

    // phase A: wave computes out[b][c] (4x2) fully; lane L ends with out[(L>>1)&3][L&1]
    auto computeA = [&]() -> float {
        float v[8];
#pragma unroll
        for (int s = 0; s < 8; ++s) v[s] = 0.f;
#pragma unroll
        for (int q = 0; q < 4; ++q) {
            float4 w0 = a_l4[(wc + Lc) * 256 + q * 64 + L];
            float4 w1 = a_l4[(wc + (1 ^ Lc)) * 256 + q * 64 + L];
#pragma unroll
            for (int r = 0; r < 4; ++r) {
                float4 hv = st4[((r ^ Lb) << 8) + q * 64 + L];
                v[r * 2 + 0] += hv.x * w0.x + hv.y * w0.y + hv.z * w0.z + hv.w * w0.w;
                v[r * 2 + 1] += hv.x * w1.x + hv.y * w1.y + hv.z * w1.z + hv.w * w1.w;
            }
        }
#pragma unroll
        for (int j = 0; j < 4; ++j) v[j] = v[2 * j] + __shfl_xor(v[2 * j + 1], 1);
#pragma unroll
        for (int j = 0; j < 2; ++j) v[j] = v[2 * j] + __shfl_xor(v[2 * j + 1], 2);
        v[0] = v[0] + __shfl_xor(v[1], 4);
        v[0] += __shfl_xor(v[0], 8);
        v[0] += __shfl_xor(v[0], 16);
        v[0] += __shfl_xor(v[0], 32);
        return v[0];
    };
    // phase B: wave computes preact[b][j][gt] (4x2x4); lane L ends with slot L&31
    auto computeB = [&]() -> float {
        float v[32];
#pragma unroll
        for (int s = 0; s < 32; ++s) v[s] = 0.f;
#pragma unroll
        for (int gt = 0; gt < 4; ++gt) {
            const int gg = gt ^ Lg;
            float4 w0 = ct_l4[(wc + Lj) * 256 + gg * 64 + L];
            float4 w1 = ct_l4[(wc + (1 ^ Lj)) * 256 + gg * 64 + L];
#pragma unroll
            for (int b = 0; b < 4; ++b) {
                float4 gv = st4[((b ^ Lbb) << 8) + gg * 64 + L];
                v[b * 8 + 0 + gt] += gv.x * w0.x + gv.y * w0.y + gv.z * w0.z + gv.w * w0.w;
                v[b * 8 + 4 + gt] += gv.x * w1.x + gv.y * w1.y + gv.z * w1.z + gv.w * w1.w;
            }
        }
#pragma unroll
        for (int j = 0; j < 16; ++j) v[j] = v[2 * j] + __shfl_xor(v[2 * j + 1], 1);
#pragma unroll
        for (int j = 0; j < 8; ++j)  v[j] = v[2 * j] + __shfl_xor(v[2 * j + 1], 2);
#pragma unroll
        for (int j = 0; j < 4; ++j)  v[j] = v[2 * j] + __shfl_xor(v[2 * j + 1], 4);
#pragma unroll
        for (int j = 0; j < 2; ++j)  v[j] = v[2 * j] + __shfl_xor(v[2 * j + 1], 8);
        v[0] = v[0] + __shfl_xor(v[1], 16);
        v[0] += __shfl_xor(v[0], 32);
        return v[0];
    };

    auto epiB = [&](float r, int bgx, float& creg, int k) {
        float y1 = __shfl_xor(r, 1), y2 = __shfl_xor(r, 2), y3 = __shfl_xor(r, 3);
        if (L < 32 && (L & 3) == 0) {
            float ft = 1.f / (1.f + __expf(-r));
            float it = 1.f / (1.f + __expf(-y1));
            float gg = tanhf(y2);
            float ot = 1.f / (1.f + __expf(-y3));
            creg = ft * creg + it * gg;
            float hv = ot * tanhf(creg);
            int bglob = bgx * 4 + b_b;
            u64 pk = ((u64)(unsigned)k << 32) | (u64)__float_as_uint(hv);
            __hip_atomic_store(hp + (size_t)(k & 1) * 32768 + (size_t)bglob * 1024 + b_col,
                               pk, __ATOMIC_RELAXED, __HIP_MEMORY_SCOPE_AGENT);
            st_uc(XBH + ((size_t)bglob * 512 + k) * 1024 + b_col, hv);
            if (k == 511) {
                st_uc(ht_out + (size_t)bglob * 1024 + b_col, hv);
                st_uc(ct_out + (size_t)bglob * 1024 + b_col, creg);
            }
        }
    };

    __syncthreads();                       // weights ready
    issue_pf(hp + 32768 + (size_t)bg0 * 4096);   // A0(0): hp slot 1 (init matches)

    for (int k = 0; k < 512; ++k) {
        const unsigned expA = (unsigned)(k - 1);
        const unsigned expB = (unsigned)k;
        const size_t hsl = (size_t)((k + 1) & 1) * 32768;
        const size_t gsl = (size_t)(k & 1) * 32768;

        float xb0 = 0.f, xb1 = 0.f;        // cached loads; line-sharing safe (own cols)
        if (L < 8) {
            xb0 = XBH[((size_t)(bg0 * 4 + a_b) * 512 + k) * 1024 + a_col];
            xb1 = XBH[((size_t)(bg1 * 4 + a_b) * 512 + k) * 1024 + a_col];
        }

        // ---- A0(k): consume h0(k-1); inline-publish g0(k); pf A1 ----
        validate_stage(hp + hsl + (size_t)bg0 * 4096, expA);
        LGKM0_BAR;                         // B1
        {
            float r = computeA();
            if (L < 8) {
                u64 pk = ((u64)expB << 32) | (u64)__float_as_uint(r * xb0);
                __hip_atomic_store(gp + gsl + (size_t)(bg0 * 4 + a_b) * 1024 + a_col,
                                   pk, __ATOMIC_RELAXED, __HIP_MEMORY_SCOPE_AGENT);
            }
        }
        issue_pf(hp + hsl + (size_t)bg1 * 4096);
        LGKM0_BAR;                         // B2

        // ---- A1(k): consume h1(k-1); inline-publish g1(k); pf B0 ----
        validate_stage(hp + hsl + (size_t)bg1 * 4096, expA);
        LGKM0_BAR;
        {
            float r = computeA();
            if (L < 8) {
                u64 pk = ((u64)expB << 32) | (u64)__float_as_uint(r * xb1);
                __hip_atomic_store(gp + gsl + (size_t)(bg1 * 4 + a_b) * 1024 + a_col,
                                   pk, __ATOMIC_RELAXED, __HIP_MEMORY_SCOPE_AGENT);
            }
        }
        issue_pf(gp + gsl + (size_t)bg0 * 4096);
        LGKM0_BAR;

        // ---- B0(k): consume g0(k); inline epi+publish h0(k); pf B1 ----
        validate_stage(gp + gsl + (size_t)bg0 * 4096, expB);
        LGKM0_BAR;
        epiB(computeB(), bg0, creg0, k);
        issue_pf(gp + gsl + (size_t)bg1 * 4096);
        LGKM0_BAR;

        // ---- B1(k): consume g1(k); inline epi+publish h1(k); pf A0(k+1) ----
        validate_stage(gp + gsl + (size_t)bg1 * 4096, expB);
        LGKM0_BAR;
        epiB(computeB(), bg1, creg1, k);
        issue_pf(hp + gsl + (size_t)bg0 * 4096);
        LGKM0_BAR;
    }
}

// ---------------------------------------------------------------- launch
extern "C" void kernel_launch(void* const* d_in, const int* in_sizes, int n_in,
                              void* d_out, int out_size, void* d_ws, size_t ws_size,
                              hipStream_t stream) {
    const float* X   = (const float*)d_in[0];
    const float* A   = (const float*)d_in[1];
    const float* Bw  = (const float*)d_in[2];
    const float* CTm = (const float*)d_in[3];

    float* out    = (float*)d_out;
    float* XBH    = out;                                  // xb in, hidden_seq out
    float* ht_out = out + (size_t)32 * 512 * 1024;
    float* ct_out = ht_out + 32 * 1024;

    u64* hp = (u64*)d_ws;                                 // 65536 pairs (512KB)
    u64* gp = hp + 65536;                                 // 65536 pairs (512KB)

    (void)hipFuncSetAttribute((const void*)scan_kernel,
                              hipFuncAttributeMaxDynamicSharedMemorySize, 81920);

    init_kernel<<<dim3(256), dim3(256), 0, stream>>>(hp, gp);
    xb_gemm<<<dim3(1024), dim3(256), 0, stream>>>(X, Bw, XBH);
    scan_kernel<<<dim3(512), dim3(256), 81920, stream>>>(A, CTm, XBH, hp, gp,
                                                         ht_out, ct_out);
}

// Round 16
// 4355.783 us; speedup vs baseline: 2.1408x; 1.4173x over previous
//
#include <hip/hip_runtime.h>
#include <math.h>

#define NTHR 512
typedef unsigned long long u64;

// ---------------------------------------------------------------- helpers
__device__ __forceinline__ void st_uc(float* p, float v) {
    asm volatile("global_store_dword %0, %1, off sc0 sc1" :: "v"(p), "v"(v) : "memory");
}
#define LGKM0_BAR do { \
    asm volatile("s_waitcnt lgkmcnt(0)" ::: "memory"); \
    __builtin_amdgcn_s_barrier(); \
} while (0)

// ---------------------------------------------------------------- init
// hp/gp: 2 slots x 32 batches x 1024 cols of (step:u32 | value:f32) pairs.
// hp counter 0xFFFFFFFF = expected at k=0 (value 0 = h(-1)); gp never-match.
__global__ void init_kernel(u64* hp, u64* gp) {
    int i = blockIdx.x * blockDim.x + threadIdx.x;
    if (i < 65536) {
        __hip_atomic_store(hp + i, 0xFFFFFFFF00000000ull, __ATOMIC_RELAXED, __HIP_MEMORY_SCOPE_AGENT);
        __hip_atomic_store(gp + i, 0xFFFFFFFE00000000ull, __ATOMIC_RELAXED, __HIP_MEMORY_SCOPE_AGENT);
    }
}

// ---------------------------------------------------------------- xb = x @ b
__global__ __launch_bounds__(256) void xb_gemm(const float* __restrict__ X,
                                               const float* __restrict__ Bw,
                                               float* __restrict__ XB) {
    __shared__ float xs[16][132];
    __shared__ float bs[16][132];
    const int bm = blockIdx.x >> 3;
    const int bn = blockIdx.x & 7;
    const int m0 = bm * 128, n0 = bn * 128;
    const int tid = threadIdx.x;
    const int tx = tid & 15, ty = tid >> 4;
    float acc[8][8];
#pragma unroll
    for (int i = 0; i < 8; ++i)
#pragma unroll
        for (int j = 0; j < 8; ++j) acc[i][j] = 0.f;

    for (int k0 = 0; k0 < 1024; k0 += 16) {
#pragma unroll
        for (int p = 0; p < 2; ++p) {
            int f = tid + p * 256;
            int m = f >> 2, kq = f & 3;
            float4 v = *(const float4*)&X[(size_t)(m0 + m) * 1024 + k0 + kq * 4];
            xs[kq * 4 + 0][m] = v.x; xs[kq * 4 + 1][m] = v.y;
            xs[kq * 4 + 2][m] = v.z; xs[kq * 4 + 3][m] = v.w;
        }
#pragma unroll
        for (int p = 0; p < 2; ++p) {
            int f = tid + p * 256;
            int k = f >> 5, n = (f & 31) * 4;
            float4 v = *(const float4*)&Bw[(size_t)(k0 + k) * 1024 + n0 + n];
            *(float4*)&bs[k][n] = v;
        }
        __syncthreads();
#pragma unroll
        for (int k = 0; k < 16; ++k) {
            float xv[8], bv[8];
            *(float4*)&xv[0] = *(const float4*)&xs[k][ty * 8];
            *(float4*)&xv[4] = *(const float4*)&xs[k][ty * 8 + 4];
            *(float4*)&bv[0] = *(const float4*)&bs[k][tx * 8];
            *(float4*)&bv[4] = *(const float4*)&bs[k][tx * 8 + 4];
#pragma unroll
            for (int i = 0; i < 8; ++i)
#pragma unroll
                for (int j = 0; j < 8; ++j) acc[i][j] += xv[i] * bv[j];
        }
        __syncthreads();
    }
#pragma unroll
    for (int i = 0; i < 8; ++i)
#pragma unroll
        for (int j = 0; j < 8; j += 4) {
            float4 v = make_float4(acc[i][j], acc[i][j + 1], acc[i][j + 2], acc[i][j + 3]);
            *(float4*)&XB[(size_t)(m0 + ty * 8 + i) * 1024 + n0 + tx * 8 + j] = v;
        }
}

// ---------------------------------------------------------------- persistent scan
// 256 WGs = 2 streams x 4 bg(4 batches) x 64 slices. In-band (value,step) pairs,
// raw lgkm-only barriers, register prefetch at end of compute (pairs in flight
// across B2 + next epi + validate). Deferred epilogues: each sub-phase's outputs
// published by one wave at the start of the NEXT sub-phase (scr ordered by B2).
// Best-verified structure (r11): survived r12-r15 challengers.
__global__ __launch_bounds__(NTHR, 1) void scan_kernel(
    const float* __restrict__ A, const float* __restrict__ CTm,
    float* __restrict__ XBH, u64* __restrict__ hp, u64* __restrict__ gp,
    float* __restrict__ ht_out, float* __restrict__ ct_out) {
    extern __shared__ float lds[];
    float* a_lf  = lds;                    // 16384 floats (64KB)
    float* ct_lf = lds + 16384;            // 16384 floats (64KB)
    float* stgf  = lds + 32768;            // 4096 floats (16KB), shared by streams
    float* scr0  = lds + 36864;            // 256 floats
    float* scr1  = lds + 37120;            // 256 floats  (149504 B total)
    const float4* a_l4  = (const float4*)a_lf;
    const float4* ct_l4 = (const float4*)ct_lf;
    float4* stg4 = (float4*)stgf;

    const int wg  = blockIdx.x;
    const int bg0 = wg >> 6;               // 0..3
    const int bg1 = bg0 + 4;               // 4..7
    const int sg  = wg & 63;
    const int c0wg = sg * 16;
    const int tid = threadIdx.x;

    // ---- one-time weight preload: cols c0wg..c0wg+15, col-major ----
    {
        const int c = tid & 15, i0 = tid >> 4;
        for (int i = i0; i < 1024; i += 32) {
            a_lf[c * 1024 + i]  = A[(size_t)i * 1024 + c0wg + c];
            ct_lf[c * 1024 + i] = CTm[(size_t)i * 1024 + c0wg + c];
        }
    }

    const int L  = tid & 63;
    const int w  = tid >> 6;
    const int Lc = L & 7;
    const int Lb = (L >> 3) & 3;
    const int cg = w & 1, kq = w >> 1;

    int wIdx[8], sIdx[4];
#pragma unroll
    for (int c = 0; c < 8; ++c) wIdx[c] = (cg * 8 + (c ^ Lc)) * 256 + kq * 64 + L;
#pragma unroll
    for (int r = 0; r < 4; ++r) sIdx[r] = ((r ^ Lb) << 8) + kq * 64 + L;

    // epilogue lane mapping: 1 output/lane (4 batches x 16 cols)
    const int e_b   = L >> 4;
    const int e_j   = L & 15;
    const int e_cgo = e_j >> 3;
    const int e_sx  = e_b * 8 + (e_j & 7);
    const int col   = c0wg + e_j;

    float creg = 0.f;                      // stream0 cell in w0, stream1 in w4
    float xbv  = 0.f;                      // stream0 xb in w1, stream1 in w2
    u64 qpf[8];                            // prefetched pairs for next sub-phase

    auto issue_pf = [&](const u64* base) {
#pragma unroll
        for (int j = 0; j < 8; ++j)
            qpf[j] = __hip_atomic_load(base + tid + 512 * j, __ATOMIC_RELAXED,
                                       __HIP_MEMORY_SCOPE_AGENT);
    };

    auto compute = [&](const float4* wmat, float* scr) {
        float4 sv[4], wv[8];
#pragma unroll
        for (int r = 0; r < 4; ++r) sv[r] = stg4[sIdx[r]];
#pragma unroll
        for (int c = 0; c < 8; ++c) wv[c] = wmat[wIdx[c]];
        float v[32];
#pragma unroll
        for (int r = 0; r < 4; ++r)
#pragma unroll
            for (int c = 0; c < 8; ++c)
                v[r * 8 + c] = sv[r].x * wv[c].x + sv[r].y * wv[c].y
                             + sv[r].z * wv[c].z + sv[r].w * wv[c].w;
#pragma unroll
        for (int j = 0; j < 16; ++j) v[j] = v[2 * j] + __shfl_xor(v[2 * j + 1], 1);
#pragma unroll
        for (int j = 0; j < 8; ++j)  v[j] = v[2 * j] + __shfl_xor(v[2 * j + 1], 2);
#pragma unroll
        for (int j = 0; j < 4; ++j)  v[j] = v[2 * j] + __shfl_xor(v[2 * j + 1], 4);
#pragma unroll
        for (int j = 0; j < 2; ++j)  v[j] = v[2 * j] + __shfl_xor(v[2 * j + 1], 8);
        v[0] = v[0] + __shfl_xor(v[1], 16);
        v[0] = v[0] + __shfl_xor(v[0], 32);
        if (L < 32) scr[kq * 64 + cg * 32 + L] = v[0];
    };

    auto epiA_fn = [&](int t, const float* s, int bgx) {      // g = (h@A)*xb
        float q = s[e_cgo * 32 + e_sx] + s[64 + e_cgo * 32 + e_sx]
                + s[128 + e_cgo * 32 + e_sx] + s[192 + e_cgo * 32 + e_sx];
        u64 pk = ((u64)(unsigned)t << 32) | (u64)__float_as_uint(q * xbv);
        __hip_atomic_store(gp + (size_t)(t & 1) * 32768 + (size_t)(bgx * 4 + e_b) * 1024 + col,
                           pk, __ATOMIC_RELAXED, __HIP_MEMORY_SCOPE_AGENT);
    };
    auto epiB_fn = [&](int t, const float* s, int bgx) {      // gates + cell
        float q0 = s[e_cgo * 32 + e_sx],       q1 = s[64 + e_cgo * 32 + e_sx];
        float q2 = s[128 + e_cgo * 32 + e_sx], q3 = s[192 + e_cgo * 32 + e_sx];
        float ft = 1.f / (1.f + __expf(-q0));
        float it = 1.f / (1.f + __expf(-q1));
        float gt = tanhf(q2);
        float ot = 1.f / (1.f + __expf(-q3));
        creg = ft * creg + it * gt;
        float hv = ot * tanhf(creg);
        int bglob = bgx * 4 + e_b;
        u64 pk = ((u64)(unsigned)t << 32) | (u64)__float_as_uint(hv);
        __hip_atomic_store(hp + (size_t)(t & 1) * 32768 + (size_t)bglob * 1024 + col,
                           pk, __ATOMIC_RELAXED, __HIP_MEMORY_SCOPE_AGENT);
        st_uc(XBH + ((size_t)bglob * 512 + t) * 1024 + col, hv);
        if (t == 511) {
            st_uc(ht_out + (size_t)bglob * 1024 + col, hv);
            st_uc(ct_out + (size_t)bglob * 1024 + col, creg);
        }
    };

    // sub-phase: pending epi -> validate prefetched pairs -> stage -> B1 ->
    // compute -> issue prefetch(next) -> B2. Raw barriers: no vmcnt drain.
    auto sub = [&](const u64* base, unsigned expect, const float4* wmat, float* scr,
                   int ek, int t, const u64* pfbase) {
        if (ek == 1) { if (w == 4 && t > 0) epiB_fn(t - 1, scr1, bg1); }
        else if (ek == 2) { if (w == 1) epiA_fn(t, scr0, bg0); }
        else if (ek == 3) { if (w == 2) epiA_fn(t, scr1, bg1); }
        else { if (w == 0) epiB_fn(t, scr0, bg0); }
        u64 q[8];
#pragma unroll
        for (int j = 0; j < 8; ++j) q[j] = qpf[j];
        for (;;) {
            bool ok = true;
#pragma unroll
            for (int j = 0; j < 8; ++j) ok &= ((unsigned)(q[j] >> 32) == expect);
            if (!__any(!ok)) break;
            __builtin_amdgcn_s_sleep(1);
#pragma unroll
            for (int j = 0; j < 8; ++j)
                q[j] = __hip_atomic_load(base + tid + 512 * j, __ATOMIC_RELAXED,
                                         __HIP_MEMORY_SCOPE_AGENT);
        }
#pragma unroll
        for (int j = 0; j < 8; ++j) stgf[tid + 512 * j] = __uint_as_float((unsigned)q[j]);
        LGKM0_BAR;                         // B1: staged (pair loads may stay in flight)
        compute(wmat, scr);
        issue_pf(pfbase);                  // next sub-phase's pairs: in flight across B2
        LGKM0_BAR;                         // B2: scr ready, staging consumed
    };

    __syncthreads();                       // weights ready (one-time, full drain ok)
    issue_pf(hp + 32768 + (size_t)bg0 * 4096);   // prologue: A0(0) pairs (slot 1)

    for (int k = 0; k < 512; ++k) {
        const unsigned expA = (unsigned)(k - 1);
        const unsigned expB = (unsigned)k;
        // xb for this iter's A-epilogues (in flight until epiA consumes)
        if (w == 1) xbv = __uint_as_float(__hip_atomic_load(
            (const unsigned*)(XBH + ((size_t)(bg0 * 4 + e_b) * 512 + k) * 1024 + col),
            __ATOMIC_RELAXED, __HIP_MEMORY_SCOPE_AGENT));
        if (w == 2) xbv = __uint_as_float(__hip_atomic_load(
            (const unsigned*)(XBH + ((size_t)(bg1 * 4 + e_b) * 512 + k) * 1024 + col),
            __ATOMIC_RELAXED, __HIP_MEMORY_SCOPE_AGENT));

        const size_t hsl = (size_t)((k + 1) & 1) * 32768;
        const size_t gsl = (size_t)(k & 1) * 32768;
        // A0(k): consume h0(k-1); pending epiB1(k-1); prefetch A1 = h1(k-1)
        sub(hp + hsl + (size_t)bg0 * 4096, expA, a_l4, scr0, 1, k,
            hp + hsl + (size_t)bg1 * 4096);
        // A1(k): consume h1(k-1); pending epiA0(k); prefetch B0 = g0(k)
        sub(hp + hsl + (size_t)bg1 * 4096, expA, a_l4, scr1, 2, k,
            gp + gsl + (size_t)bg0 * 4096);
        // B0(k): consume g0(k); pending epiA1(k); prefetch B1 = g1(k)
        sub(gp + gsl + (size_t)bg0 * 4096, expB, ct_l4, scr0, 3, k,
            gp + gsl + (size_t)bg1 * 4096);
        // B1(k): consume g1(k); pending epiB0(k); prefetch A0(k+1) = h0(k)
        sub(gp + gsl + (size_t)bg1 * 4096, expB, ct_l4, scr1, 4, k,
            hp + (size_t)(k & 1) * 32768 + (size_t)bg0 * 4096);
    }
    // tail: epiB1(511) (scr1 from B1(511), ordered by its B2)
    if (w == 4) epiB_fn(511, scr1, bg1);
}

// ---------------------------------------------------------------- launch
extern "C" void kernel_launch(void* const* d_in, const int* in_sizes, int n_in,
                              void* d_out, int out_size, void* d_ws, size_t ws_size,
                              hipStream_t stream) {
    const float* X   = (const float*)d_in[0];
    const float* A   = (const float*)d_in[1];
    const float* Bw  = (const float*)d_in[2];
    const float* CTm = (const float*)d_in[3];

    float* out    = (float*)d_out;
    float* XBH    = out;                                  // xb in, hidden_seq out
    float* ht_out = out + (size_t)32 * 512 * 1024;
    float* ct_out = ht_out + 32 * 1024;

    u64* hp = (u64*)d_ws;                                 // 65536 pairs (512KB)
    u64* gp = hp + 65536;                                 // 65536 pairs (512KB)

    (void)hipFuncSetAttribute((const void*)scan_kernel,
                              hipFuncAttributeMaxDynamicSharedMemorySize, 149504);

    init_kernel<<<dim3(256), dim3(256), 0, stream>>>(hp, gp);
    xb_gemm<<<dim3(1024), dim3(256), 0, stream>>>(X, Bw, XBH);
    scan_kernel<<<dim3(256), dim3(NTHR), 149504, stream>>>(A, CTm, XBH, hp, gp,
                                                           ht_out, ct_out);
}